// Round 1
// baseline (1369.625 us; speedup 1.0000x reference)
//
#include <hip/hip_runtime.h>
#include <cstdint>
#include <cstddef>

// ---------------------------------------------------------------------------
// Problem constants: B=2, C=128, D=H=W=32, nh=8, hd=16, L=32
// Tokens: t = b*32768 + d*1024 + h*32 + w   (65536 tokens, 128 channels)
// ---------------------------------------------------------------------------

#define NTOK 65536
#define SPAT 32768

// ws offsets (in floats)
#define WS_A      0ull          // 8388608  : lf -> x_mod -> attention accum
#define WS_B      8388608ull    // 8388608  : m_pre (dies before qkv written)
#define WS_C      8388608ull    // 25165824 : qkv [t][384] (overlaps dead B)
#define WS_WT     33554432ull   // 442368   : lp_w1 transposed [dz][dy][ci][dx][co]
#define WS_QKVWT  33996800ull   // 49152    : qkv_w^T [i][o]
#define WS_WCT    34045952ull   // 16384    : (mod_w1@lp_w2)^T [i][o]
#define WS_MODW2T 34062336ull   // 16384
#define WS_PROJWT 34078720ull   // 16384
#define WS_BC     34095104ull   // 128      : combined bias
#define WS_RBUF   34095232ull   // 432      : [axial][head][18] (Rqk 9, Rv 9)
#define WS_PS     34095664ull   // 32768    : per-block partial sums
#define WS_PSS    34128432ull   // 32768
#define WS_MU1    34161200ull   // 256
#define WS_RS1    34161456ull   // 256
#define WS_MU2    34161712ull   // 256
#define WS_RS2    34161968ull   // 256
// total 34162224 floats = 136.6 MB

__device__ __forceinline__ float gelu_f(float x) {
  return 0.5f * x * (1.0f + erff(x * 0.70710678118654752f));
}
__device__ __forceinline__ float sigmoid_f(float x) {
  return 1.0f / (1.0f + expf(-x));
}
__device__ __forceinline__ float dot3(const float* a, const float* b) {
  return a[0] * b[0] + a[1] * b[1] + a[2] * b[2];
}
__device__ __forceinline__ void cross3(const float* a, const float* b, float* c) {
  c[0] = a[1] * b[2] - a[2] * b[1];
  c[1] = a[2] * b[0] - a[0] * b[2];
  c[2] = a[0] * b[1] - a[1] * b[0];
}

// exact port of _r6_to_matrix for one head (6 floats in, 9 out row-major)
__device__ void r6_to_matrix(const float* r6, float* R) {
  float v1[3] = {r6[0], r6[1], r6[2]};
  float n1 = sqrtf(dot3(v1, v1));
  float inv1 = 1.0f / (n1 + 1e-7f);
  v1[0] *= inv1; v1[1] *= inv1; v1[2] *= inv1;
  float v2[3] = {r6[3], r6[4], r6[5]};
  float d = dot3(v2, v1);
  v2[0] -= d * v1[0]; v2[1] -= d * v1[1]; v2[2] -= d * v1[2];
  float n2 = sqrtf(dot3(v2, v2));
  float inv2 = 1.0f / (n2 + 1e-7f);
  v2[0] *= inv2; v2[1] *= inv2; v2[2] *= inv2;
  float v3[3]; cross3(v1, v2, v3);
  float cx[3]; cross3(v2, v3, cx);
  float det = dot3(v1, cx);
  if (det < 0.0f) { v3[0] = -v3[0]; v3[1] = -v3[1]; v3[2] = -v3[2]; }
  R[0] = v1[0]; R[1] = v1[1]; R[2] = v1[2];
  R[3] = v2[0]; R[4] = v2[1]; R[5] = v2[2];
  R[6] = v3[0]; R[7] = v3[1]; R[8] = v3[2];
}

// exact port of _ensure_matrix for one head (9 in row-major, 9 out)
__device__ void ensure_matrix(const float* Rin, float* Ro) {
  float a[3] = {Rin[0] + 1e-6f, Rin[1] + 1e-6f, Rin[2] + 1e-6f};
  float na = fmaxf(sqrtf(dot3(a, a)), 1e-12f);
  float v1[3] = {a[0] / na, a[1] / na, a[2] / na};
  float b0[3] = {Rin[3], Rin[4], Rin[5]};
  float d = dot3(b0, v1);
  float bb[3] = {b0[0] - d * v1[0] + 1e-6f, b0[1] - d * v1[1] + 1e-6f, b0[2] - d * v1[2] + 1e-6f};
  float nb = fmaxf(sqrtf(dot3(bb, bb)), 1e-12f);
  float v2[3] = {bb[0] / nb, bb[1] / nb, bb[2] / nb};
  float v3[3]; cross3(v1, v2, v3);
  float cx[3]; cross3(v2, v3, cx);
  float det = dot3(v1, cx);
  if (det < 0.0f) { v3[0] = -v3[0]; v3[1] = -v3[1]; v3[2] = -v3[2]; }
  float Rn[9] = {v1[0], v1[1], v1[2], v2[0], v2[1], v2[2], v3[0], v3[1], v3[2]};
  // T1 = Rn^T @ Rn ; T2 = T1 @ Rn^T ; Ro = 0.5*(Rn + T2)
  float T1[9], T2[9];
  for (int i = 0; i < 3; ++i)
    for (int j = 0; j < 3; ++j) {
      float s = 0.f;
      for (int k = 0; k < 3; ++k) s += Rn[k * 3 + i] * Rn[k * 3 + j];
      T1[i * 3 + j] = s;
    }
  for (int i = 0; i < 3; ++i)
    for (int j = 0; j < 3; ++j) {
      float s = 0.f;
      for (int k = 0; k < 3; ++k) s += T1[i * 3 + k] * Rn[j * 3 + k];
      T2[i * 3 + j] = s;
    }
  for (int i = 0; i < 9; ++i) Ro[i] = 0.5f * (Rn[i] + T2[i]);
}

// ---------------------------------------------------------------------------
// K0: rotation matrices for 3 axials x 8 heads
// ---------------------------------------------------------------------------
__global__ void prep_r_kernel(const float* __restrict__ Ad, const float* __restrict__ Ah,
                              const float* __restrict__ Aw, const float* __restrict__ Rd,
                              const float* __restrict__ Rh, const float* __restrict__ Rw,
                              float* __restrict__ Rbuf) {
  int tid = threadIdx.x;
  if (tid >= 24) return;
  int ax = tid >> 3, h = tid & 7;
  const float* A = (ax == 0) ? Ad : ((ax == 1) ? Ah : Aw);
  const float* R = (ax == 0) ? Rd : ((ax == 1) ? Rh : Rw);
  float Rq[9], Rv[9];
  r6_to_matrix(A + h * 6, Rq);
  ensure_matrix(R + h * 9, Rv);
  float* dst = Rbuf + (ax * 8 + h) * 18;
  for (int i = 0; i < 9; ++i) { dst[i] = Rq[i]; dst[9 + i] = Rv[i]; }
}

// ---------------------------------------------------------------------------
// K0b: weight transposes + fused (mod_w1 @ lp_w2) matrix
// ---------------------------------------------------------------------------
__global__ __launch_bounds__(256) void prep_w_kernel(
    const float* __restrict__ lp_w1, const float* __restrict__ qkv_w,
    const float* __restrict__ mod_w1, const float* __restrict__ lp_w2,
    const float* __restrict__ lp_b2, const float* __restrict__ mod_b1,
    const float* __restrict__ mod_w2, const float* __restrict__ proj_w,
    float* __restrict__ wT, float* __restrict__ qkvWt, float* __restrict__ WcT,
    float* __restrict__ modw2T, float* __restrict__ projWt, float* __restrict__ bc) {
  int gid = blockIdx.x * 256 + threadIdx.x;  // 65536 threads
  // lp_w1T[((dz*3+dy)*128 + ci)*3 + dx][co]
  for (int f = gid; f < 442368; f += 65536) {
    int co = f & 127;
    int r = f >> 7;
    int dx = r % 3;
    int r2 = r / 3;
    int ci = r2 & 127;
    int r3 = r2 >> 7;
    int dy = r3 % 3, dz = r3 / 3;
    wT[f] = lp_w1[(co * 128 + ci) * 27 + dz * 9 + dy * 3 + dx];
  }
  // qkvWt[i][o], 128x384
  for (int f = gid; f < 49152; f += 65536) {
    int o = f % 384, i = f / 384;
    qkvWt[f] = qkv_w[o * 128 + i];
  }
  if (gid < 16384) {
    int o = gid & 127, i = gid >> 7;
    modw2T[gid] = mod_w2[o * 128 + i];
    projWt[gid] = proj_w[o * 128 + i];
    float s = 0.f;
    for (int c = 0; c < 128; ++c) s += mod_w1[o * 128 + c] * lp_w2[c * 128 + i];
    WcT[gid] = s;  // WcT[i][o]
  }
  if (gid < 128) {
    float s = 0.f;
    for (int c = 0; c < 128; ++c) s += mod_w1[gid * 128 + c] * lp_b2[c];
    bc[gid] = s + mod_b1[gid];
  }
}

// ---------------------------------------------------------------------------
// K1: 3x3x3 circular conv, pos_emb (NCDHW) -> lf token-major [t][128]
// block = (b,d,h) row; 256 threads; thread tile 2w x 8co
// ---------------------------------------------------------------------------
__global__ __launch_bounds__(256) void conv_kernel(const float* __restrict__ in,
                                                   const float* __restrict__ wT,
                                                   const float* __restrict__ b1,
                                                   float* __restrict__ out) {
  __shared__ float in_lds[128][32];
  __shared__ float w_lds[6144];  // [ci_local(16)][dx(3)][co(128)]
  int blk = blockIdx.x;
  int b = blk >> 10, d = (blk >> 5) & 31, h = blk & 31;
  int tid = threadIdx.x;
  int wg = tid & 15, cog = tid >> 4;
  int w0 = wg * 2, co0 = cog * 8;
  float4 bv0 = *(const float4*)(b1 + co0);
  float4 bv1 = *(const float4*)(b1 + co0 + 4);
  float acc[2][8];
  for (int wl = 0; wl < 2; ++wl) {
    acc[wl][0] = bv0.x; acc[wl][1] = bv0.y; acc[wl][2] = bv0.z; acc[wl][3] = bv0.w;
    acc[wl][4] = bv1.x; acc[wl][5] = bv1.y; acc[wl][6] = bv1.z; acc[wl][7] = bv1.w;
  }
  for (int dz = 0; dz < 3; ++dz) {
    int zr = (d + dz + 31) & 31;
    for (int dy = 0; dy < 3; ++dy) {
      int yr = (h + dy + 31) & 31;
      __syncthreads();
      const float* src = in + (size_t)b * 128 * SPAT + zr * 1024 + yr * 32;
      #pragma unroll
      for (int r = 0; r < 16; ++r) {
        int idx = r * 256 + tid;
        int ci = idx >> 5, ww = idx & 31;
        in_lds[ci][ww] = src[(size_t)ci * SPAT + ww];
      }
      int tapbase = ((dz * 3 + dy) * 128) * 384;
      for (int cb = 0; cb < 8; ++cb) {
        __syncthreads();
        const float* wsrc = wT + tapbase + cb * 16 * 384;
        #pragma unroll
        for (int r = 0; r < 24; ++r) w_lds[r * 256 + tid] = wsrc[r * 256 + tid];
        __syncthreads();
        #pragma unroll
        for (int cl = 0; cl < 16; ++cl) {
          int ci = cb * 16 + cl;
          float iv[4];
          #pragma unroll
          for (int j = 0; j < 4; ++j) iv[j] = in_lds[ci][(w0 + j + 31) & 31];
          #pragma unroll
          for (int dx = 0; dx < 3; ++dx) {
            float4 wv0 = *(float4*)&w_lds[(cl * 3 + dx) * 128 + co0];
            float4 wv1 = *(float4*)&w_lds[(cl * 3 + dx) * 128 + co0 + 4];
            float wa[8] = {wv0.x, wv0.y, wv0.z, wv0.w, wv1.x, wv1.y, wv1.z, wv1.w};
            #pragma unroll
            for (int wl = 0; wl < 2; ++wl) {
              float inval = iv[wl + dx];
              #pragma unroll
              for (int j = 0; j < 8; ++j) acc[wl][j] += inval * wa[j];
            }
          }
        }
      }
    }
  }
  size_t tbase = ((size_t)b << 15) + (d << 10) + (h << 5);
  #pragma unroll
  for (int wl = 0; wl < 2; ++wl) {
    size_t t = tbase + w0 + wl;
    float4 r0 = {acc[wl][0], acc[wl][1], acc[wl][2], acc[wl][3]};
    float4 r1 = {acc[wl][4], acc[wl][5], acc[wl][6], acc[wl][7]};
    *(float4*)(out + t * 128 + co0) = r0;
    *(float4*)(out + t * 128 + co0 + 4) = r1;
  }
}

// ---------------------------------------------------------------------------
// K2: instance-norm partial sums (deterministic two-pass)
// ---------------------------------------------------------------------------
__global__ __launch_bounds__(256) void stats_partial_kernel(const float* __restrict__ buf,
                                                            float* __restrict__ ps,
                                                            float* __restrict__ pss) {
  __shared__ float l1[256], l2[256];
  int blk = blockIdx.x;  // 256 blocks of 256 tokens
  int tid = threadIdx.x;
  int c = tid & 127, half = tid >> 7;
  size_t t0 = (size_t)blk * 256;
  float s = 0.f, ss = 0.f;
  for (int i = half; i < 256; i += 2) {
    float v = buf[(t0 + i) * 128 + c];
    s += v;
    ss += v * v;
  }
  l1[tid] = s; l2[tid] = ss;
  __syncthreads();
  if (half == 0) {
    ps[blk * 128 + c] = s + l1[tid + 128];
    pss[blk * 128 + c] = ss + l2[tid + 128];
  }
}

__global__ void stats_final_kernel(const float* __restrict__ ps, const float* __restrict__ pss,
                                   float* __restrict__ mu, float* __restrict__ rs) {
  int tid = threadIdx.x;  // 256 threads, 1 block; tid = b*128 + c
  int b = tid >> 7, c = tid & 127;
  float s = 0.f, ss = 0.f;
  for (int blk = b * 128; blk < b * 128 + 128; ++blk) {
    s += ps[blk * 128 + c];
    ss += pss[blk * 128 + c];
  }
  float m = s * (1.0f / 32768.0f);
  float v = ss * (1.0f / 32768.0f) - m * m;
  mu[tid] = m;
  rs[tid] = rsqrtf(v + 1e-5f);
}

// ---------------------------------------------------------------------------
// GEMM: Y[t][o] = post( pre(A[t][:]) @ Wt[:][o] + bias[o] )
// PRE:  0 none | 1 gelu(instance-norm)
// POST: 0 plain token-major store | 1 sigmoid * x (NCDHW gather) | 2 NCDHW store
// tile 64t x 64o, BK=16, 256 threads, thread tile 4x4
// ---------------------------------------------------------------------------
template <int PRE, int POST>
__global__ __launch_bounds__(256) void gemm_kernel(const float* __restrict__ Ap,
                                                   const float* __restrict__ Wt,
                                                   const float* __restrict__ bias,
                                                   float* __restrict__ Y, int O,
                                                   const float* __restrict__ mu,
                                                   const float* __restrict__ rs,
                                                   const float* __restrict__ xin) {
  __shared__ float As[16][68];
  __shared__ float Bs[16][64];
  const int tid = threadIdx.x;
  const int tb = blockIdx.x, ob = blockIdx.y;
  const int tt = tid >> 4, to = tid & 15;
  const int t0 = tb * 64;
  const int og = ob * 64;
  const int sa_t = tid >> 2, sa_k = (tid & 3) * 4;
  const int sb_k = tid >> 4, sb_o = (tid & 15) * 4;
  const int bidx = t0 >> 15;
  float acc[4][4] = {};
  for (int kb = 0; kb < 128; kb += 16) {
    __syncthreads();
    float4 av = *(const float4*)(Ap + (size_t)(t0 + sa_t) * 128 + kb + sa_k);
    if constexpr (PRE == 1) {
      const float4 m4 = *(const float4*)(mu + bidx * 128 + kb + sa_k);
      const float4 r4 = *(const float4*)(rs + bidx * 128 + kb + sa_k);
      av.x = gelu_f((av.x - m4.x) * r4.x);
      av.y = gelu_f((av.y - m4.y) * r4.y);
      av.z = gelu_f((av.z - m4.z) * r4.z);
      av.w = gelu_f((av.w - m4.w) * r4.w);
    }
    As[sa_k + 0][sa_t] = av.x;
    As[sa_k + 1][sa_t] = av.y;
    As[sa_k + 2][sa_t] = av.z;
    As[sa_k + 3][sa_t] = av.w;
    *(float4*)&Bs[sb_k][sb_o] = *(const float4*)(Wt + (size_t)(kb + sb_k) * O + og + sb_o);
    __syncthreads();
    #pragma unroll
    for (int k = 0; k < 16; ++k) {
      const float4 a4 = *(const float4*)&As[k][tt * 4];
      const float4 b4 = *(const float4*)&Bs[k][to * 4];
      const float aa[4] = {a4.x, a4.y, a4.z, a4.w};
      const float bb[4] = {b4.x, b4.y, b4.z, b4.w};
      #pragma unroll
      for (int i = 0; i < 4; ++i)
        #pragma unroll
        for (int j = 0; j < 4; ++j) acc[i][j] += aa[i] * bb[j];
    }
  }
  const float4 bv = *(const float4*)(bias + og + to * 4);
  const float bbias[4] = {bv.x, bv.y, bv.z, bv.w};
  #pragma unroll
  for (int i = 0; i < 4; ++i) {
    const int t = t0 + tt * 4 + i;
    if constexpr (POST == 0) {
      float4 r = {acc[i][0] + bbias[0], acc[i][1] + bbias[1], acc[i][2] + bbias[2],
                  acc[i][3] + bbias[3]};
      *(float4*)(Y + (size_t)t * O + og + to * 4) = r;
    } else if constexpr (POST == 1) {
      const int dhw = t & 32767, bB = t >> 15;
      float vals[4];
      #pragma unroll
      for (int j = 0; j < 4; ++j) {
        const int o = og + to * 4 + j;
        const float xv = xin[((size_t)(bB * 128 + o) << 15) + dhw];
        vals[j] = sigmoid_f(acc[i][j] + bbias[j]) * xv;
      }
      float4 r = {vals[0], vals[1], vals[2], vals[3]};
      *(float4*)(Y + (size_t)t * 128 + og + to * 4) = r;
    } else {
      const int dhw = t & 32767, bB = t >> 15;
      #pragma unroll
      for (int j = 0; j < 4; ++j) {
        const int o = og + to * 4 + j;
        Y[((size_t)(bB * 128 + o) << 15) + dhw] = acc[i][j] + bbias[j];
      }
    }
  }
}

// ---------------------------------------------------------------------------
// K7: axial attention. One wave per (seq, head-pair); half-wave per head.
// Lane = (head half, token/query). L=32, hd=16.
// pa term and row-constant bias terms cancel in softmax; effective logit:
//   q_r . k_r * 0.25 - lin[k] * pos_bias_w[comp]
// ---------------------------------------------------------------------------
__device__ __forceinline__ void rot16(const float* R, const float* x, float* y) {
  #pragma unroll
  for (int g = 0; g < 5; ++g) {
    float a = x[3 * g], b = x[3 * g + 1], c = x[3 * g + 2];
    y[3 * g + 0] = R[0] * a + R[1] * b + R[2] * c;
    y[3 * g + 1] = R[3] * a + R[4] * b + R[5] * c;
    y[3 * g + 2] = R[6] * a + R[7] * b + R[8] * c;
  }
  y[15] = R[0] * x[15];  // padded vector (x15,0,0): only row0 col0 survives
}

template <int ACCUM>
__global__ __launch_bounds__(64) void attn_kernel(const float* __restrict__ qkv,
                                                  const float* __restrict__ Rbuf,
                                                  const float* __restrict__ pbw,
                                                  float* __restrict__ accum, int axial) {
  __shared__ float Klds[2][32][20];
  __shared__ float Vlds[2][32][20];
  int seq = blockIdx.x, hp = blockIdx.y;
  int lane = threadIdx.x;
  int hh = lane >> 5;
  int head = hp * 2 + hh;
  int tok = lane & 31;
  int b = seq >> 10, rem = seq & 1023;
  int u = rem >> 5, v = rem & 31;
  int base, stride, comp;
  if (axial == 0) { base = (b << 15) + (u << 5) + v;  stride = 1024; comp = 2; }  // along D
  else if (axial == 1) { base = (b << 15) + (u << 10) + v; stride = 32; comp = 1; }  // along H
  else { base = (b << 15) + (u << 10) + (v << 5); stride = 1; comp = 0; }  // along W
  const float* Rp = Rbuf + (axial * 8 + head) * 18;
  float Rq[9], Rv[9];
  #pragma unroll
  for (int i = 0; i < 9; ++i) { Rq[i] = Rp[i]; Rv[i] = Rp[9 + i]; }
  size_t t_tok = (size_t)base + (size_t)tok * stride;
  const float* row = qkv + t_tok * 384 + head * 16;
  float xq[16], xk[16], xv[16];
  #pragma unroll
  for (int j = 0; j < 4; ++j) {
    float4 a = *(const float4*)(row + j * 4);
    float4 bq = *(const float4*)(row + 128 + j * 4);
    float4 cq = *(const float4*)(row + 256 + j * 4);
    xq[j * 4] = a.x; xq[j * 4 + 1] = a.y; xq[j * 4 + 2] = a.z; xq[j * 4 + 3] = a.w;
    xk[j * 4] = bq.x; xk[j * 4 + 1] = bq.y; xk[j * 4 + 2] = bq.z; xk[j * 4 + 3] = bq.w;
    xv[j * 4] = cq.x; xv[j * 4 + 1] = cq.y; xv[j * 4 + 2] = cq.z; xv[j * 4 + 3] = cq.w;
  }
  float qr[16], kr[16], vr[16];
  rot16(Rq, xq, qr);
  rot16(Rq, xk, kr);
  rot16(Rv, xv, vr);
  #pragma unroll
  for (int j = 0; j < 16; ++j) { Klds[hh][tok][j] = kr[j]; Vlds[hh][tok][j] = vr[j]; }
  __syncthreads();
  float wb = pbw[comp];
  float s[32];
  #pragma unroll
  for (int k = 0; k < 32; ++k) {
    const float* kp = &Klds[hh][k][0];
    float dot = 0.f;
    #pragma unroll
    for (int j = 0; j < 16; ++j) dot += qr[j] * kp[j];
    float lin = -1.0f + (2.0f / 31.0f) * (float)k;
    s[k] = dot * 0.25f - lin * wb;
  }
  float m = s[0];
  #pragma unroll
  for (int k = 1; k < 32; ++k) m = fmaxf(m, s[k]);
  float sum = 0.f;
  #pragma unroll
  for (int k = 0; k < 32; ++k) { s[k] = expf(s[k] - m); sum += s[k]; }
  float inv = 1.0f / sum;
  float o[16];
  #pragma unroll
  for (int j = 0; j < 16; ++j) o[j] = 0.f;
  #pragma unroll
  for (int k = 0; k < 32; ++k) {
    float p = s[k];
    const float* vp = &Vlds[hh][k][0];
    #pragma unroll
    for (int j = 0; j < 16; ++j) o[j] += p * vp[j];
  }
  float* dst = accum + t_tok * 128 + head * 16;
  if (ACCUM == 0) {
    #pragma unroll
    for (int j = 0; j < 16; ++j) dst[j] = o[j] * inv;
  } else {
    #pragma unroll
    for (int j = 0; j < 16; ++j) dst[j] += o[j] * inv;
  }
}

// ---------------------------------------------------------------------------
extern "C" void kernel_launch(void* const* d_in, const int* in_sizes, int n_in,
                              void* d_out, int out_size, void* d_ws, size_t ws_size,
                              hipStream_t stream) {
  const float* x       = (const float*)d_in[0];
  const float* pos_emb = (const float*)d_in[1];
  const float* qkv_w   = (const float*)d_in[2];
  const float* qkv_b   = (const float*)d_in[3];
  const float* lp_w1   = (const float*)d_in[4];
  const float* lp_b1   = (const float*)d_in[5];
  const float* lp_w2   = (const float*)d_in[6];
  const float* lp_b2   = (const float*)d_in[7];
  const float* mod_w1  = (const float*)d_in[8];
  const float* mod_b1  = (const float*)d_in[9];
  const float* mod_w2  = (const float*)d_in[10];
  const float* mod_b2  = (const float*)d_in[11];
  // d_in[12] pa_w, d_in[13] pa_b: cancel in softmax (constant along key axis)
  const float* proj_w  = (const float*)d_in[14];
  const float* proj_b  = (const float*)d_in[15];
  const float* pbw     = (const float*)d_in[16];
  // d_in[17] pos_bias_b: cancels in softmax
  const float* Ad      = (const float*)d_in[18];
  const float* Ah      = (const float*)d_in[19];
  const float* Aw      = (const float*)d_in[20];
  const float* Rd      = (const float*)d_in[21];
  const float* Rh      = (const float*)d_in[22];
  const float* Rw      = (const float*)d_in[23];
  // d_in[24..26] t_d/t_h/t_w: cancel in rel (pairwise difference)

  float* ws = (float*)d_ws;
  float* A      = ws + WS_A;
  float* Bb     = ws + WS_B;
  float* C      = ws + WS_C;
  float* wT     = ws + WS_WT;
  float* qkvWt  = ws + WS_QKVWT;
  float* WcT    = ws + WS_WCT;
  float* modw2T = ws + WS_MODW2T;
  float* projWt = ws + WS_PROJWT;
  float* bc     = ws + WS_BC;
  float* Rbuf   = ws + WS_RBUF;
  float* ps     = ws + WS_PS;
  float* pss    = ws + WS_PSS;
  float* mu1    = ws + WS_MU1;
  float* rs1    = ws + WS_RS1;
  float* mu2    = ws + WS_MU2;
  float* rs2    = ws + WS_RS2;

  prep_r_kernel<<<1, 64, 0, stream>>>(Ad, Ah, Aw, Rd, Rh, Rw, Rbuf);
  prep_w_kernel<<<256, 256, 0, stream>>>(lp_w1, qkv_w, mod_w1, lp_w2, lp_b2, mod_b1,
                                         mod_w2, proj_w, wT, qkvWt, WcT, modw2T, projWt, bc);
  // lf = circular conv3x3x3(pos_emb)
  conv_kernel<<<2048, 256, 0, stream>>>(pos_emb, wT, lp_b1, A);
  // m_pre = gelu(inorm(lf)) @ Wc^T + bc
  stats_partial_kernel<<<256, 256, 0, stream>>>(A, ps, pss);
  stats_final_kernel<<<1, 256, 0, stream>>>(ps, pss, mu1, rs1);
  gemm_kernel<1, 0><<<dim3(1024, 2), 256, 0, stream>>>(A, WcT, bc, Bb, 128, mu1, rs1, nullptr);
  // x_mod = x * sigmoid(gelu(inorm(m_pre)) @ mod_w2^T + mod_b2)
  stats_partial_kernel<<<256, 256, 0, stream>>>(Bb, ps, pss);
  stats_final_kernel<<<1, 256, 0, stream>>>(ps, pss, mu2, rs2);
  gemm_kernel<1, 1><<<dim3(1024, 2), 256, 0, stream>>>(Bb, modw2T, mod_b2, A, 128, mu2, rs2, x);
  // qkv = x_mod @ qkv_w^T + qkv_b  (shared across all three axials)
  gemm_kernel<0, 0><<<dim3(1024, 6), 256, 0, stream>>>(A, qkvWt, qkv_b, C, 384, nullptr, nullptr, nullptr);
  // three axial attentions, accumulated into A (x_mod is dead now)
  attn_kernel<0><<<dim3(2048, 4), 64, 0, stream>>>(C, Rbuf, pbw, A, 0);
  attn_kernel<1><<<dim3(2048, 4), 64, 0, stream>>>(C, Rbuf, pbw, A, 1);
  attn_kernel<1><<<dim3(2048, 4), 64, 0, stream>>>(C, Rbuf, pbw, A, 2);
  // final projection -> NCDHW output
  gemm_kernel<0, 2><<<dim3(1024, 2), 256, 0, stream>>>(A, projWt, proj_b, (float*)d_out, 128,
                                                       nullptr, nullptr, nullptr);
}

// Round 2
// 597.778 us; speedup vs baseline: 2.2912x; 2.2912x over previous
//
#include <hip/hip_runtime.h>
#include <cstdint>
#include <cstddef>

// ---------------------------------------------------------------------------
// Problem constants: B=2, C=128, D=H=W=32, nh=8, hd=16, L=32
// Tokens: t = b*32768 + d*1024 + h*32 + w   (65536 tokens, 128 channels)
// ---------------------------------------------------------------------------

#define NTOK 65536
#define SPAT 32768

// ws offsets (in floats)
#define WS_A      0ull          // 8388608  : lf -> x_mod -> attention accum
#define WS_B      8388608ull    // 8388608  : inT (bf16 pos_emb) -> m_pre
#define WS_C      8388608ull    // 25165824 : qkv [t][384] (overlaps dead B)
#define WS_WT     33554432ull   // region: Bpack bf16 [tap][co][dx*128+ci] (442368 ushort)
#define WS_QKVWT  33996800ull   // 49152   : qkv_w^T [i][o]
#define WS_WCT    34045952ull   // 16384   : (mod_w1@lp_w2)^T [i][o]
#define WS_MODW2T 34062336ull   // 16384
#define WS_PROJWT 34078720ull   // 16384
#define WS_BC     34095104ull   // 128     : combined bias
#define WS_RBUF   34095232ull   // 432     : [axial][head][18] (Rqk 9, Rv 9)
#define WS_PS     34095664ull   // 32768   : per-block partial sums
#define WS_PSS    34128432ull   // 32768
#define WS_MU1    34161200ull   // 256
#define WS_RS1    34161456ull   // 256
#define WS_MU2    34161712ull   // 256
#define WS_RS2    34161968ull   // 256
// total 34162224 floats = 136.6 MB

typedef __attribute__((ext_vector_type(8))) short short8;
typedef __attribute__((ext_vector_type(4))) float f32x4;

__device__ __forceinline__ float gelu_f(float x) {
  return 0.5f * x * (1.0f + erff(x * 0.70710678118654752f));
}
__device__ __forceinline__ float sigmoid_f(float x) {
  return 1.0f / (1.0f + expf(-x));
}
__device__ __forceinline__ unsigned short f2bf(float x) {  // RNE f32->bf16
  unsigned int u = __float_as_uint(x);
  unsigned int r = u + 0x7fffu + ((u >> 16) & 1u);
  return (unsigned short)(r >> 16);
}
__device__ __forceinline__ float dot3(const float* a, const float* b) {
  return a[0] * b[0] + a[1] * b[1] + a[2] * b[2];
}
__device__ __forceinline__ void cross3(const float* a, const float* b, float* c) {
  c[0] = a[1] * b[2] - a[2] * b[1];
  c[1] = a[2] * b[0] - a[0] * b[2];
  c[2] = a[0] * b[1] - a[1] * b[0];
}

// exact port of _r6_to_matrix for one head (6 floats in, 9 out row-major)
__device__ void r6_to_matrix(const float* r6, float* R) {
  float v1[3] = {r6[0], r6[1], r6[2]};
  float n1 = sqrtf(dot3(v1, v1));
  float inv1 = 1.0f / (n1 + 1e-7f);
  v1[0] *= inv1; v1[1] *= inv1; v1[2] *= inv1;
  float v2[3] = {r6[3], r6[4], r6[5]};
  float d = dot3(v2, v1);
  v2[0] -= d * v1[0]; v2[1] -= d * v1[1]; v2[2] -= d * v1[2];
  float n2 = sqrtf(dot3(v2, v2));
  float inv2 = 1.0f / (n2 + 1e-7f);
  v2[0] *= inv2; v2[1] *= inv2; v2[2] *= inv2;
  float v3[3]; cross3(v1, v2, v3);
  float cx[3]; cross3(v2, v3, cx);
  float det = dot3(v1, cx);
  if (det < 0.0f) { v3[0] = -v3[0]; v3[1] = -v3[1]; v3[2] = -v3[2]; }
  R[0] = v1[0]; R[1] = v1[1]; R[2] = v1[2];
  R[3] = v2[0]; R[4] = v2[1]; R[5] = v2[2];
  R[6] = v3[0]; R[7] = v3[1]; R[8] = v3[2];
}

// exact port of _ensure_matrix for one head (9 in row-major, 9 out)
__device__ void ensure_matrix(const float* Rin, float* Ro) {
  float a[3] = {Rin[0] + 1e-6f, Rin[1] + 1e-6f, Rin[2] + 1e-6f};
  float na = fmaxf(sqrtf(dot3(a, a)), 1e-12f);
  float v1[3] = {a[0] / na, a[1] / na, a[2] / na};
  float b0[3] = {Rin[3], Rin[4], Rin[5]};
  float d = dot3(b0, v1);
  float bb[3] = {b0[0] - d * v1[0] + 1e-6f, b0[1] - d * v1[1] + 1e-6f, b0[2] - d * v1[2] + 1e-6f};
  float nb = fmaxf(sqrtf(dot3(bb, bb)), 1e-12f);
  float v2[3] = {bb[0] / nb, bb[1] / nb, bb[2] / nb};
  float v3[3]; cross3(v1, v2, v3);
  float cx[3]; cross3(v2, v3, cx);
  float det = dot3(v1, cx);
  if (det < 0.0f) { v3[0] = -v3[0]; v3[1] = -v3[1]; v3[2] = -v3[2]; }
  float Rn[9] = {v1[0], v1[1], v1[2], v2[0], v2[1], v2[2], v3[0], v3[1], v3[2]};
  float T1[9], T2[9];
  for (int i = 0; i < 3; ++i)
    for (int j = 0; j < 3; ++j) {
      float s = 0.f;
      for (int k = 0; k < 3; ++k) s += Rn[k * 3 + i] * Rn[k * 3 + j];
      T1[i * 3 + j] = s;
    }
  for (int i = 0; i < 3; ++i)
    for (int j = 0; j < 3; ++j) {
      float s = 0.f;
      for (int k = 0; k < 3; ++k) s += T1[i * 3 + k] * Rn[j * 3 + k];
      T2[i * 3 + j] = s;
    }
  for (int i = 0; i < 9; ++i) Ro[i] = 0.5f * (Rn[i] + T2[i]);
}

// ---------------------------------------------------------------------------
// K0: rotation matrices for 3 axials x 8 heads
// ---------------------------------------------------------------------------
__global__ void prep_r_kernel(const float* __restrict__ Ad, const float* __restrict__ Ah,
                              const float* __restrict__ Aw, const float* __restrict__ Rd,
                              const float* __restrict__ Rh, const float* __restrict__ Rw,
                              float* __restrict__ Rbuf) {
  int tid = threadIdx.x;
  if (tid >= 24) return;
  int ax = tid >> 3, h = tid & 7;
  const float* A = (ax == 0) ? Ad : ((ax == 1) ? Ah : Aw);
  const float* R = (ax == 0) ? Rd : ((ax == 1) ? Rh : Rw);
  float Rq[9], Rv[9];
  r6_to_matrix(A + h * 6, Rq);
  ensure_matrix(R + h * 9, Rv);
  float* dst = Rbuf + (ax * 8 + h) * 18;
  for (int i = 0; i < 9; ++i) { dst[i] = Rq[i]; dst[9 + i] = Rv[i]; }
}

// ---------------------------------------------------------------------------
// K0b: weight packs + fused (mod_w1 @ lp_w2) matrix
//   Bpack (bf16): [tap2=dz*3+dy][co][dx*128+ci]  for the MFMA conv
// ---------------------------------------------------------------------------
__global__ __launch_bounds__(256) void prep_w_kernel(
    const float* __restrict__ lp_w1, const float* __restrict__ qkv_w,
    const float* __restrict__ mod_w1, const float* __restrict__ lp_w2,
    const float* __restrict__ lp_b2, const float* __restrict__ mod_b1,
    const float* __restrict__ mod_w2, const float* __restrict__ proj_w,
    unsigned short* __restrict__ Bp, float* __restrict__ qkvWt, float* __restrict__ WcT,
    float* __restrict__ modw2T, float* __restrict__ projWt, float* __restrict__ bc) {
  int gid = blockIdx.x * 256 + threadIdx.x;  // 65536 threads
  // Bpack[((tap*128 + co)*3 + dx)*128 + ci]
  for (int f = gid; f < 442368; f += 65536) {
    int ci = f & 127;
    int rr = f >> 7;        // (tap*128+co)*3 + dx
    int dx = rr % 3;
    int r2 = rr / 3;        // tap*128 + co
    int co = r2 & 127;
    int tap = r2 >> 7;
    int dz = tap / 3, dy = tap % 3;
    Bp[f] = f2bf(lp_w1[(co * 128 + ci) * 27 + dz * 9 + dy * 3 + dx]);
  }
  // qkvWt[i][o], 128x384
  for (int f = gid; f < 49152; f += 65536) {
    int o = f % 384, i = f / 384;
    qkvWt[f] = qkv_w[o * 128 + i];
  }
  if (gid < 16384) {
    int o = gid & 127, i = gid >> 7;
    modw2T[gid] = mod_w2[o * 128 + i];
    projWt[gid] = proj_w[o * 128 + i];
    float s = 0.f;
    for (int c = 0; c < 128; ++c) s += mod_w1[o * 128 + c] * lp_w2[c * 128 + i];
    WcT[gid] = s;  // WcT[i][o]
  }
  if (gid < 128) {
    float s = 0.f;
    for (int c = 0; c < 128; ++c) s += mod_w1[gid * 128 + c] * lp_b2[c];
    bc[gid] = s + mod_b1[gid];
  }
}

// ---------------------------------------------------------------------------
// K0c: pos_emb NCDHW fp32 -> token-major bf16 inT[t][ci]
// one block per (b,d,h) row: 32 w x 128 ci, LDS transpose
// ---------------------------------------------------------------------------
__global__ __launch_bounds__(256) void tobf16_kernel(const float* __restrict__ in,
                                                     unsigned short* __restrict__ outT) {
  __shared__ unsigned short lds[32][130];
  int blk = blockIdx.x;  // b*1024 + d*32 + h
  int b = blk >> 10;
  int dh = blk & 1023;
  int tid = threadIdx.x;
  size_t planebase = ((size_t)b << 22) + ((size_t)dh << 5);
  #pragma unroll
  for (int r = 0; r < 16; ++r) {
    int idx = r * 256 + tid;
    int ci = idx >> 5, w = idx & 31;
    lds[w][ci] = f2bf(in[planebase + ((size_t)ci << 15) + w]);
  }
  __syncthreads();
  size_t tb = ((size_t)blk) << 5;
  #pragma unroll
  for (int r = 0; r < 16; ++r) {
    int idx = r * 256 + tid;
    int w = idx >> 7, ci = idx & 127;
    outT[(tb + w) * 128 + ci] = lds[w][ci];
  }
}

// ---------------------------------------------------------------------------
// K1: 3x3x3 circular conv via bf16 MFMA (fp32 accumulate)
// Block: 128 tokens (4 h-rows x 32 w) x 128 co. 4 waves, 2x2, 64x64 each.
// A staged in LDS (XOR-swizzled via pre-swizzled global source);
// B fragments read straight from L2-resident Bpack.
// ---------------------------------------------------------------------------
__global__ __launch_bounds__(256) void conv_mfma_kernel(const unsigned short* __restrict__ inT,
                                                        const unsigned short* __restrict__ Bp,
                                                        const float* __restrict__ b1,
                                                        float* __restrict__ out) {
  __shared__ unsigned short Als[16384];  // 32 KB: 128 tok x 128 ci bf16, swizzled
  const int blk = blockIdx.x;
  const int b = blk >> 8, d = (blk >> 3) & 31, hg = blk & 7;
  const int h0 = hg << 2;
  const int tid = threadIdx.x;
  const int lane = tid & 63, wid = tid >> 6;
  const int wm = wid >> 1, wn = wid & 1;
  const int l15 = lane & 15, l4 = lane >> 4;

  f32x4 acc[4][4];
  #pragma unroll
  for (int mt = 0; mt < 4; ++mt)
    #pragma unroll
    for (int nt = 0; nt < 4; ++nt)
      #pragma unroll
      for (int r = 0; r < 4; ++r) acc[mt][nt][r] = 0.f;

  // A-fragment lds addressing (per mt, before dx shift): token = hh*32 + w
  int mbase[4], mw[4], mhh[4];
  #pragma unroll
  for (int mt = 0; mt < 4; ++mt) {
    int m = wm * 64 + mt * 16 + l15;
    mhh[mt] = m >> 5;
    mw[mt] = m & 31;
    mbase[mt] = 0;
  }
  const size_t tokbase = ((size_t)b << 15) + ((size_t)d << 10) + ((size_t)h0 << 5);

  for (int tap = 0; tap < 9; ++tap) {
    const int dz = tap / 3, dy = tap % 3;
    const int zr = (d + dz + 31) & 31;
    __syncthreads();
    // stage A: 128 tokens x 128 ci bf16 = 32 KB, source-swizzled
    #pragma unroll
    for (int p = 0; p < 8; ++p) {
      int g = p * 256 + tid;
      int tok = g >> 4, gi = g & 15;
      int hh = tok >> 5, w = tok & 31;
      int yr = (h0 + hh + dy + 31) & 31;
      size_t srcbyte = ((((size_t)b << 15) + ((size_t)zr << 10) + ((size_t)yr << 5) + w) << 8)
                       + (size_t)((gi ^ (w & 7)) << 4);
      uint4 v = *(const uint4*)((const char*)inT + srcbyte);
      *(uint4*)((char*)Als + g * 16) = v;
    }
    __syncthreads();
    // B row bases for this tap
    int brow[4];
    #pragma unroll
    for (int nt = 0; nt < 4; ++nt) {
      int co = wn * 64 + nt * 16 + l15;
      brow[nt] = (tap * 128 + co) * 384;
    }
    #pragma unroll
    for (int dx = 0; dx < 3; ++dx) {
      int abase[4], asw[4];
      #pragma unroll
      for (int mt = 0; mt < 4; ++mt) {
        int wsft = (mw[mt] + dx + 31) & 31;
        int stok = mhh[mt] * 32 + wsft;
        abase[mt] = stok * 256;
        asw[mt] = (stok & 7) << 4;
      }
      #pragma unroll
      for (int ks = 0; ks < 4; ++ks) {
        const int k2 = (ks * 32 + l4 * 8) * 2;           // byte offset within ci row
        const int koff = dx * 128 + ks * 32 + l4 * 8;    // element offset in Bpack row
        short8 afr[4], bfr[4];
        #pragma unroll
        for (int mt = 0; mt < 4; ++mt)
          afr[mt] = *(const short8*)((const char*)Als + abase[mt] + (k2 ^ asw[mt]));
        #pragma unroll
        for (int nt = 0; nt < 4; ++nt)
          bfr[nt] = *(const short8*)(Bp + brow[nt] + koff);
        #pragma unroll
        for (int mt = 0; mt < 4; ++mt)
          #pragma unroll
          for (int nt = 0; nt < 4; ++nt)
            acc[mt][nt] = __builtin_amdgcn_mfma_f32_16x16x32_bf16(afr[mt], bfr[nt],
                                                                  acc[mt][nt], 0, 0, 0);
      }
    }
  }
  // epilogue: + bias, store fp32 token-major
  #pragma unroll
  for (int nt = 0; nt < 4; ++nt) {
    const int co = wn * 64 + nt * 16 + l15;
    const float bias = b1[co];
    #pragma unroll
    for (int mt = 0; mt < 4; ++mt) {
      #pragma unroll
      for (int r = 0; r < 4; ++r) {
        int m = wm * 64 + mt * 16 + l4 * 4 + r;
        out[(tokbase + m) * 128 + co] = acc[mt][nt][r] + bias;
      }
    }
  }
}

// ---------------------------------------------------------------------------
// K2: instance-norm partial sums (deterministic two-pass)
// ---------------------------------------------------------------------------
__global__ __launch_bounds__(256) void stats_partial_kernel(const float* __restrict__ buf,
                                                            float* __restrict__ ps,
                                                            float* __restrict__ pss) {
  __shared__ float l1[256], l2[256];
  int blk = blockIdx.x;  // 256 blocks of 256 tokens
  int tid = threadIdx.x;
  int c = tid & 127, half = tid >> 7;
  size_t t0 = (size_t)blk * 256;
  float s = 0.f, ss = 0.f;
  for (int i = half; i < 256; i += 2) {
    float v = buf[(t0 + i) * 128 + c];
    s += v;
    ss += v * v;
  }
  l1[tid] = s; l2[tid] = ss;
  __syncthreads();
  if (half == 0) {
    ps[blk * 128 + c] = s + l1[tid + 128];
    pss[blk * 128 + c] = ss + l2[tid + 128];
  }
}

__global__ void stats_final_kernel(const float* __restrict__ ps, const float* __restrict__ pss,
                                   float* __restrict__ mu, float* __restrict__ rs) {
  int tid = threadIdx.x;  // 256 threads, 1 block; tid = b*128 + c
  int b = tid >> 7, c = tid & 127;
  float s = 0.f, ss = 0.f;
  for (int blk = b * 128; blk < b * 128 + 128; ++blk) {
    s += ps[blk * 128 + c];
    ss += pss[blk * 128 + c];
  }
  float m = s * (1.0f / 32768.0f);
  float v = ss * (1.0f / 32768.0f) - m * m;
  mu[tid] = m;
  rs[tid] = rsqrtf(v + 1e-5f);
}

// ---------------------------------------------------------------------------
// GEMM: Y[t][o] = post( pre(A[t][:]) @ Wt[:][o] + bias[o] )
// PRE:  0 none | 1 gelu(instance-norm)
// POST: 0 plain token-major store | 1 sigmoid * x (NCDHW gather) | 2 NCDHW store
// tile 64t x 64o, BK=16, 256 threads, thread tile 4x4
// ---------------------------------------------------------------------------
template <int PRE, int POST>
__global__ __launch_bounds__(256) void gemm_kernel(const float* __restrict__ Ap,
                                                   const float* __restrict__ Wt,
                                                   const float* __restrict__ bias,
                                                   float* __restrict__ Y, int O,
                                                   const float* __restrict__ mu,
                                                   const float* __restrict__ rs,
                                                   const float* __restrict__ xin) {
  __shared__ float As[16][68];
  __shared__ float Bs[16][64];
  const int tid = threadIdx.x;
  const int tb = blockIdx.x, ob = blockIdx.y;
  const int tt = tid >> 4, to = tid & 15;
  const int t0 = tb * 64;
  const int og = ob * 64;
  const int sa_t = tid >> 2, sa_k = (tid & 3) * 4;
  const int sb_k = tid >> 4, sb_o = (tid & 15) * 4;
  const int bidx = t0 >> 15;
  float acc[4][4] = {};
  for (int kb = 0; kb < 128; kb += 16) {
    __syncthreads();
    float4 av = *(const float4*)(Ap + (size_t)(t0 + sa_t) * 128 + kb + sa_k);
    if constexpr (PRE == 1) {
      const float4 m4 = *(const float4*)(mu + bidx * 128 + kb + sa_k);
      const float4 r4 = *(const float4*)(rs + bidx * 128 + kb + sa_k);
      av.x = gelu_f((av.x - m4.x) * r4.x);
      av.y = gelu_f((av.y - m4.y) * r4.y);
      av.z = gelu_f((av.z - m4.z) * r4.z);
      av.w = gelu_f((av.w - m4.w) * r4.w);
    }
    As[sa_k + 0][sa_t] = av.x;
    As[sa_k + 1][sa_t] = av.y;
    As[sa_k + 2][sa_t] = av.z;
    As[sa_k + 3][sa_t] = av.w;
    *(float4*)&Bs[sb_k][sb_o] = *(const float4*)(Wt + (size_t)(kb + sb_k) * O + og + sb_o);
    __syncthreads();
    #pragma unroll
    for (int k = 0; k < 16; ++k) {
      const float4 a4 = *(const float4*)&As[k][tt * 4];
      const float4 b4 = *(const float4*)&Bs[k][to * 4];
      const float aa[4] = {a4.x, a4.y, a4.z, a4.w};
      const float bb[4] = {b4.x, b4.y, b4.z, b4.w};
      #pragma unroll
      for (int i = 0; i < 4; ++i)
        #pragma unroll
        for (int j = 0; j < 4; ++j) acc[i][j] += aa[i] * bb[j];
    }
  }
  const float4 bv = *(const float4*)(bias + og + to * 4);
  const float bbias[4] = {bv.x, bv.y, bv.z, bv.w};
  #pragma unroll
  for (int i = 0; i < 4; ++i) {
    const int t = t0 + tt * 4 + i;
    if constexpr (POST == 0) {
      float4 r = {acc[i][0] + bbias[0], acc[i][1] + bbias[1], acc[i][2] + bbias[2],
                  acc[i][3] + bbias[3]};
      *(float4*)(Y + (size_t)t * O + og + to * 4) = r;
    } else if constexpr (POST == 1) {
      const int dhw = t & 32767, bB = t >> 15;
      float vals[4];
      #pragma unroll
      for (int j = 0; j < 4; ++j) {
        const int o = og + to * 4 + j;
        const float xv = xin[((size_t)(bB * 128 + o) << 15) + dhw];
        vals[j] = sigmoid_f(acc[i][j] + bbias[j]) * xv;
      }
      float4 r = {vals[0], vals[1], vals[2], vals[3]};
      *(float4*)(Y + (size_t)t * 128 + og + to * 4) = r;
    } else {
      const int dhw = t & 32767, bB = t >> 15;
      #pragma unroll
      for (int j = 0; j < 4; ++j) {
        const int o = og + to * 4 + j;
        Y[((size_t)(bB * 128 + o) << 15) + dhw] = acc[i][j] + bbias[j];
      }
    }
  }
}

// ---------------------------------------------------------------------------
// K7: axial attention. One wave per (seq, head-pair); half-wave per head.
// pa term and row-constant bias terms cancel in softmax; effective logit:
//   q_r . k_r * 0.25 - lin[k] * pos_bias_w[comp]
// ---------------------------------------------------------------------------
__device__ __forceinline__ void rot16(const float* R, const float* x, float* y) {
  #pragma unroll
  for (int g = 0; g < 5; ++g) {
    float a = x[3 * g], b = x[3 * g + 1], c = x[3 * g + 2];
    y[3 * g + 0] = R[0] * a + R[1] * b + R[2] * c;
    y[3 * g + 1] = R[3] * a + R[4] * b + R[5] * c;
    y[3 * g + 2] = R[6] * a + R[7] * b + R[8] * c;
  }
  y[15] = R[0] * x[15];  // padded vector (x15,0,0): only row0 col0 survives
}

template <int ACCUM>
__global__ __launch_bounds__(64) void attn_kernel(const float* __restrict__ qkv,
                                                  const float* __restrict__ Rbuf,
                                                  const float* __restrict__ pbw,
                                                  float* __restrict__ accum, int axial) {
  __shared__ float Klds[2][32][20];
  __shared__ float Vlds[2][32][20];
  int seq = blockIdx.x, hp = blockIdx.y;
  int lane = threadIdx.x;
  int hh = lane >> 5;
  int head = hp * 2 + hh;
  int tok = lane & 31;
  int b = seq >> 10, rem = seq & 1023;
  int u = rem >> 5, v = rem & 31;
  int base, stride, comp;
  if (axial == 0) { base = (b << 15) + (u << 5) + v;  stride = 1024; comp = 2; }
  else if (axial == 1) { base = (b << 15) + (u << 10) + v; stride = 32; comp = 1; }
  else { base = (b << 15) + (u << 10) + (v << 5); stride = 1; comp = 0; }
  const float* Rp = Rbuf + (axial * 8 + head) * 18;
  float Rq[9], Rv[9];
  #pragma unroll
  for (int i = 0; i < 9; ++i) { Rq[i] = Rp[i]; Rv[i] = Rp[9 + i]; }
  size_t t_tok = (size_t)base + (size_t)tok * stride;
  const float* row = qkv + t_tok * 384 + head * 16;
  float xq[16], xk[16], xv[16];
  #pragma unroll
  for (int j = 0; j < 4; ++j) {
    float4 a = *(const float4*)(row + j * 4);
    float4 bq = *(const float4*)(row + 128 + j * 4);
    float4 cq = *(const float4*)(row + 256 + j * 4);
    xq[j * 4] = a.x; xq[j * 4 + 1] = a.y; xq[j * 4 + 2] = a.z; xq[j * 4 + 3] = a.w;
    xk[j * 4] = bq.x; xk[j * 4 + 1] = bq.y; xk[j * 4 + 2] = bq.z; xk[j * 4 + 3] = bq.w;
    xv[j * 4] = cq.x; xv[j * 4 + 1] = cq.y; xv[j * 4 + 2] = cq.z; xv[j * 4 + 3] = cq.w;
  }
  float qr[16], kr[16], vr[16];
  rot16(Rq, xq, qr);
  rot16(Rq, xk, kr);
  rot16(Rv, xv, vr);
  #pragma unroll
  for (int j = 0; j < 16; ++j) { Klds[hh][tok][j] = kr[j]; Vlds[hh][tok][j] = vr[j]; }
  __syncthreads();
  float wb = pbw[comp];
  float s[32];
  #pragma unroll
  for (int k = 0; k < 32; ++k) {
    const float* kp = &Klds[hh][k][0];
    float dot = 0.f;
    #pragma unroll
    for (int j = 0; j < 16; ++j) dot += qr[j] * kp[j];
    float lin = -1.0f + (2.0f / 31.0f) * (float)k;
    s[k] = dot * 0.25f - lin * wb;
  }
  float m = s[0];
  #pragma unroll
  for (int k = 1; k < 32; ++k) m = fmaxf(m, s[k]);
  float sum = 0.f;
  #pragma unroll
  for (int k = 0; k < 32; ++k) { s[k] = expf(s[k] - m); sum += s[k]; }
  float inv = 1.0f / sum;
  float o[16];
  #pragma unroll
  for (int j = 0; j < 16; ++j) o[j] = 0.f;
  #pragma unroll
  for (int k = 0; k < 32; ++k) {
    float p = s[k];
    const float* vp = &Vlds[hh][k][0];
    #pragma unroll
    for (int j = 0; j < 16; ++j) o[j] += p * vp[j];
  }
  float* dst = accum + t_tok * 128 + head * 16;
  if (ACCUM == 0) {
    #pragma unroll
    for (int j = 0; j < 16; ++j) dst[j] = o[j] * inv;
  } else {
    #pragma unroll
    for (int j = 0; j < 16; ++j) dst[j] += o[j] * inv;
  }
}

// ---------------------------------------------------------------------------
extern "C" void kernel_launch(void* const* d_in, const int* in_sizes, int n_in,
                              void* d_out, int out_size, void* d_ws, size_t ws_size,
                              hipStream_t stream) {
  const float* x       = (const float*)d_in[0];
  const float* pos_emb = (const float*)d_in[1];
  const float* qkv_w   = (const float*)d_in[2];
  const float* qkv_b   = (const float*)d_in[3];
  const float* lp_w1   = (const float*)d_in[4];
  const float* lp_b1   = (const float*)d_in[5];
  const float* lp_w2   = (const float*)d_in[6];
  const float* lp_b2   = (const float*)d_in[7];
  const float* mod_w1  = (const float*)d_in[8];
  const float* mod_b1  = (const float*)d_in[9];
  const float* mod_w2  = (const float*)d_in[10];
  const float* mod_b2  = (const float*)d_in[11];
  // d_in[12] pa_w, d_in[13] pa_b: cancel in softmax (constant along key axis)
  const float* proj_w  = (const float*)d_in[14];
  const float* proj_b  = (const float*)d_in[15];
  const float* pbw     = (const float*)d_in[16];
  // d_in[17] pos_bias_b: cancels in softmax
  const float* Ad      = (const float*)d_in[18];
  const float* Ah      = (const float*)d_in[19];
  const float* Aw      = (const float*)d_in[20];
  const float* Rd      = (const float*)d_in[21];
  const float* Rh      = (const float*)d_in[22];
  const float* Rw      = (const float*)d_in[23];
  // d_in[24..26] t_d/t_h/t_w: cancel in rel (pairwise difference)

  float* ws = (float*)d_ws;
  float* A      = ws + WS_A;
  float* Bb     = ws + WS_B;
  float* C      = ws + WS_C;
  unsigned short* Bpack = (unsigned short*)(ws + WS_WT);
  unsigned short* inT   = (unsigned short*)(ws + WS_B);  // dead once Bb is written
  float* qkvWt  = ws + WS_QKVWT;
  float* WcT    = ws + WS_WCT;
  float* modw2T = ws + WS_MODW2T;
  float* projWt = ws + WS_PROJWT;
  float* bc     = ws + WS_BC;
  float* Rbuf   = ws + WS_RBUF;
  float* ps     = ws + WS_PS;
  float* pss    = ws + WS_PSS;
  float* mu1    = ws + WS_MU1;
  float* rs1    = ws + WS_RS1;
  float* mu2    = ws + WS_MU2;
  float* rs2    = ws + WS_RS2;

  prep_r_kernel<<<1, 64, 0, stream>>>(Ad, Ah, Aw, Rd, Rh, Rw, Rbuf);
  prep_w_kernel<<<256, 256, 0, stream>>>(lp_w1, qkv_w, mod_w1, lp_w2, lp_b2, mod_b1,
                                         mod_w2, proj_w, Bpack, qkvWt, WcT, modw2T, projWt, bc);
  // pos_emb -> token-major bf16
  tobf16_kernel<<<2048, 256, 0, stream>>>(pos_emb, inT);
  // lf = circular conv3x3x3(pos_emb), bf16 MFMA
  conv_mfma_kernel<<<512, 256, 0, stream>>>(inT, Bpack, lp_b1, A);
  // m_pre = gelu(inorm(lf)) @ Wc^T + bc
  stats_partial_kernel<<<256, 256, 0, stream>>>(A, ps, pss);
  stats_final_kernel<<<1, 256, 0, stream>>>(ps, pss, mu1, rs1);
  gemm_kernel<1, 0><<<dim3(1024, 2), 256, 0, stream>>>(A, WcT, bc, Bb, 128, mu1, rs1, nullptr);
  // x_mod = x * sigmoid(gelu(inorm(m_pre)) @ mod_w2^T + mod_b2)
  stats_partial_kernel<<<256, 256, 0, stream>>>(Bb, ps, pss);
  stats_final_kernel<<<1, 256, 0, stream>>>(ps, pss, mu2, rs2);
  gemm_kernel<1, 1><<<dim3(1024, 2), 256, 0, stream>>>(Bb, modw2T, mod_b2, A, 128, mu2, rs2, x);
  // qkv = x_mod @ qkv_w^T + qkv_b  (shared across all three axials)
  gemm_kernel<0, 0><<<dim3(1024, 6), 256, 0, stream>>>(A, qkvWt, qkv_b, C, 384, nullptr, nullptr, nullptr);
  // three axial attentions, accumulated into A (x_mod is dead now)
  attn_kernel<0><<<dim3(2048, 4), 64, 0, stream>>>(C, Rbuf, pbw, A, 0);
  attn_kernel<1><<<dim3(2048, 4), 64, 0, stream>>>(C, Rbuf, pbw, A, 1);
  attn_kernel<1><<<dim3(2048, 4), 64, 0, stream>>>(C, Rbuf, pbw, A, 2);
  // final projection -> NCDHW output
  gemm_kernel<0, 2><<<dim3(1024, 2), 256, 0, stream>>>(A, projWt, proj_b, (float*)d_out, 128,
                                                       nullptr, nullptr, nullptr);
}

// Round 3
// 511.090 us; speedup vs baseline: 2.6798x; 1.1696x over previous
//
#include <hip/hip_runtime.h>
#include <cstdint>
#include <cstddef>

// ---------------------------------------------------------------------------
// Problem constants: B=2, C=128, D=H=W=32, nh=8, hd=16, L=32
// Tokens: t = b*32768 + d*1024 + h*32 + w   (65536 tokens, 128 channels)
// ---------------------------------------------------------------------------

#define NTOK 65536
#define SPAT 32768

// ws offsets (floats). Timeline reuse:
//   R0   : lf (conv out) -> x_mod (gate gemm out) -> attention accum
//   MPRE : m_pre (Wc gemm out); XTOK : token-major x; INT : bf16 pos_emb
//   QKV  : spans MPRE/XTOK/INT (all dead before qkv gemm writes)
#define WS_R0     0ull          // 8388608
#define WS_MPRE   8388608ull    // 8388608
#define WS_XTOK   16777216ull   // 8388608
#define WS_INT    25165824ull   // 4194304 (8388608 ushorts)
#define WS_QKV    8388608ull    // 25165824 : qkv [t][384]
#define WS_CONVP  33554432ull   // 221184 (442368 ush) conv weights bf16
#define WS_QKVP   33775616ull   // 24576  (49152 ush)  qkv_w bf16 [o][i]
#define WS_WCP    33800192ull   // 8192   (16384 ush)  (mod_w1@lp_w2) bf16 [o][i]
#define WS_MODW2P 33808384ull   // 8192
#define WS_PROJP  33816576ull   // 8192
#define WS_BC     33824768ull   // 128    combined bias
#define WS_RBUF   33824896ull   // 432    [axial][head][18]
#define WS_PS     33825328ull   // 32768
#define WS_PSS    33858096ull   // 32768
#define WS_MU1    33890864ull   // 256
#define WS_RS1    33891120ull   // 256
#define WS_MU2    33891376ull   // 256
#define WS_RS2    33891632ull   // 256
// total 33891888 floats = 135.6 MB

typedef __attribute__((ext_vector_type(8))) short short8;
typedef __attribute__((ext_vector_type(4))) float f32x4;

__device__ __forceinline__ float gelu_f(float x) {
  return 0.5f * x * (1.0f + erff(x * 0.70710678118654752f));
}
__device__ __forceinline__ float sigmoid_f(float x) {
  return 1.0f / (1.0f + expf(-x));
}
__device__ __forceinline__ unsigned short f2bf(float x) {  // RNE f32->bf16
  unsigned int u = __float_as_uint(x);
  unsigned int r = u + 0x7fffu + ((u >> 16) & 1u);
  return (unsigned short)(r >> 16);
}
__device__ __forceinline__ short8 pack_bf8(float4 v0, float4 v1) {
  short8 r;
  r[0] = (short)f2bf(v0.x); r[1] = (short)f2bf(v0.y);
  r[2] = (short)f2bf(v0.z); r[3] = (short)f2bf(v0.w);
  r[4] = (short)f2bf(v1.x); r[5] = (short)f2bf(v1.y);
  r[6] = (short)f2bf(v1.z); r[7] = (short)f2bf(v1.w);
  return r;
}
__device__ __forceinline__ float dot3(const float* a, const float* b) {
  return a[0] * b[0] + a[1] * b[1] + a[2] * b[2];
}
__device__ __forceinline__ void cross3(const float* a, const float* b, float* c) {
  c[0] = a[1] * b[2] - a[2] * b[1];
  c[1] = a[2] * b[0] - a[0] * b[2];
  c[2] = a[0] * b[1] - a[1] * b[0];
}

// exact port of _r6_to_matrix for one head (6 floats in, 9 out row-major)
__device__ void r6_to_matrix(const float* r6, float* R) {
  float v1[3] = {r6[0], r6[1], r6[2]};
  float n1 = sqrtf(dot3(v1, v1));
  float inv1 = 1.0f / (n1 + 1e-7f);
  v1[0] *= inv1; v1[1] *= inv1; v1[2] *= inv1;
  float v2[3] = {r6[3], r6[4], r6[5]};
  float d = dot3(v2, v1);
  v2[0] -= d * v1[0]; v2[1] -= d * v1[1]; v2[2] -= d * v1[2];
  float n2 = sqrtf(dot3(v2, v2));
  float inv2 = 1.0f / (n2 + 1e-7f);
  v2[0] *= inv2; v2[1] *= inv2; v2[2] *= inv2;
  float v3[3]; cross3(v1, v2, v3);
  float cx[3]; cross3(v2, v3, cx);
  float det = dot3(v1, cx);
  if (det < 0.0f) { v3[0] = -v3[0]; v3[1] = -v3[1]; v3[2] = -v3[2]; }
  R[0] = v1[0]; R[1] = v1[1]; R[2] = v1[2];
  R[3] = v2[0]; R[4] = v2[1]; R[5] = v2[2];
  R[6] = v3[0]; R[7] = v3[1]; R[8] = v3[2];
}

// exact port of _ensure_matrix for one head (9 in row-major, 9 out)
__device__ void ensure_matrix(const float* Rin, float* Ro) {
  float a[3] = {Rin[0] + 1e-6f, Rin[1] + 1e-6f, Rin[2] + 1e-6f};
  float na = fmaxf(sqrtf(dot3(a, a)), 1e-12f);
  float v1[3] = {a[0] / na, a[1] / na, a[2] / na};
  float b0[3] = {Rin[3], Rin[4], Rin[5]};
  float d = dot3(b0, v1);
  float bb[3] = {b0[0] - d * v1[0] + 1e-6f, b0[1] - d * v1[1] + 1e-6f, b0[2] - d * v1[2] + 1e-6f};
  float nb = fmaxf(sqrtf(dot3(bb, bb)), 1e-12f);
  float v2[3] = {bb[0] / nb, bb[1] / nb, bb[2] / nb};
  float v3[3]; cross3(v1, v2, v3);
  float cx[3]; cross3(v2, v3, cx);
  float det = dot3(v1, cx);
  if (det < 0.0f) { v3[0] = -v3[0]; v3[1] = -v3[1]; v3[2] = -v3[2]; }
  float Rn[9] = {v1[0], v1[1], v1[2], v2[0], v2[1], v2[2], v3[0], v3[1], v3[2]};
  float T1[9], T2[9];
  for (int i = 0; i < 3; ++i)
    for (int j = 0; j < 3; ++j) {
      float s = 0.f;
      for (int k = 0; k < 3; ++k) s += Rn[k * 3 + i] * Rn[k * 3 + j];
      T1[i * 3 + j] = s;
    }
  for (int i = 0; i < 3; ++i)
    for (int j = 0; j < 3; ++j) {
      float s = 0.f;
      for (int k = 0; k < 3; ++k) s += T1[i * 3 + k] * Rn[j * 3 + k];
      T2[i * 3 + j] = s;
    }
  for (int i = 0; i < 9; ++i) Ro[i] = 0.5f * (Rn[i] + T2[i]);
}

// ---------------------------------------------------------------------------
// K0: rotation matrices for 3 axials x 8 heads
// ---------------------------------------------------------------------------
__global__ void prep_r_kernel(const float* __restrict__ Ad, const float* __restrict__ Ah,
                              const float* __restrict__ Aw, const float* __restrict__ Rd,
                              const float* __restrict__ Rh, const float* __restrict__ Rw,
                              float* __restrict__ Rbuf) {
  int tid = threadIdx.x;
  if (tid >= 24) return;
  int ax = tid >> 3, h = tid & 7;
  const float* A = (ax == 0) ? Ad : ((ax == 1) ? Ah : Aw);
  const float* R = (ax == 0) ? Rd : ((ax == 1) ? Rh : Rw);
  float Rq[9], Rv[9];
  r6_to_matrix(A + h * 6, Rq);
  ensure_matrix(R + h * 9, Rv);
  float* dst = Rbuf + (ax * 8 + h) * 18;
  for (int i = 0; i < 9; ++i) { dst[i] = Rq[i]; dst[9 + i] = Rv[i]; }
}

// ---------------------------------------------------------------------------
// K0b: bf16 weight packs + fused (mod_w1 @ lp_w2) matrix
//   convP: [tap=dz*3+dy][co][dx*128+ci] bf16
//   qkvP/WcP/modw2P/projP: [o][i] bf16 (source layouts already [o][i])
// ---------------------------------------------------------------------------
__global__ __launch_bounds__(256) void prep_w_kernel(
    const float* __restrict__ lp_w1, const float* __restrict__ qkv_w,
    const float* __restrict__ mod_w1, const float* __restrict__ lp_w2,
    const float* __restrict__ lp_b2, const float* __restrict__ mod_b1,
    const float* __restrict__ mod_w2, const float* __restrict__ proj_w,
    unsigned short* __restrict__ convP, unsigned short* __restrict__ qkvP,
    unsigned short* __restrict__ WcP, unsigned short* __restrict__ modw2P,
    unsigned short* __restrict__ projP, float* __restrict__ bc) {
  int gid = blockIdx.x * 256 + threadIdx.x;  // 65536 threads
  for (int f = gid; f < 442368; f += 65536) {
    int ci = f & 127;
    int rr = f >> 7;        // (tap*128+co)*3 + dx
    int dx = rr % 3;
    int r2 = rr / 3;
    int co = r2 & 127;
    int tap = r2 >> 7;
    int dz = tap / 3, dy = tap % 3;
    convP[f] = f2bf(lp_w1[(co * 128 + ci) * 27 + dz * 9 + dy * 3 + dx]);
  }
  if (gid < 49152) qkvP[gid] = f2bf(qkv_w[gid]);
  if (gid < 16384) {
    modw2P[gid] = f2bf(mod_w2[gid]);
    projP[gid] = f2bf(proj_w[gid]);
    int o = gid >> 7, i = gid & 127;
    float s = 0.f;
    for (int c = 0; c < 128; ++c) s += mod_w1[o * 128 + c] * lp_w2[c * 128 + i];
    WcP[gid] = f2bf(s);
  }
  if (gid < 128) {
    float s = 0.f;
    for (int c = 0; c < 128; ++c) s += mod_w1[gid * 128 + c] * lp_b2[c];
    bc[gid] = s + mod_b1[gid];
  }
}

// ---------------------------------------------------------------------------
// K0c: pos_emb NCDHW fp32 -> token-major bf16 inT[t][ci]
// ---------------------------------------------------------------------------
__global__ __launch_bounds__(256) void tobf16_kernel(const float* __restrict__ in,
                                                     unsigned short* __restrict__ outT) {
  __shared__ unsigned short lds[32][130];
  int blk = blockIdx.x;  // b*1024 + d*32 + h
  int b = blk >> 10;
  int dh = blk & 1023;
  int tid = threadIdx.x;
  size_t planebase = ((size_t)b << 22) + ((size_t)dh << 5);
  #pragma unroll
  for (int r = 0; r < 16; ++r) {
    int idx = r * 256 + tid;
    int ci = idx >> 5, w = idx & 31;
    lds[w][ci] = f2bf(in[planebase + ((size_t)ci << 15) + w]);
  }
  __syncthreads();
  size_t tb = ((size_t)blk) << 5;
  #pragma unroll
  for (int r = 0; r < 16; ++r) {
    int idx = r * 256 + tid;
    int w = idx >> 7, ci = idx & 127;
    outT[(tb + w) * 128 + ci] = lds[w][ci];
  }
}

// ---------------------------------------------------------------------------
// K0d: x NCDHW fp32 -> token-major fp32 x_tok[t][ci] (for gate epilogue)
// ---------------------------------------------------------------------------
__global__ __launch_bounds__(256) void xT_kernel(const float* __restrict__ in,
                                                 float* __restrict__ outT) {
  __shared__ float lds[32][129];
  int blk = blockIdx.x;
  int b = blk >> 10;
  int dh = blk & 1023;
  int tid = threadIdx.x;
  size_t planebase = ((size_t)b << 22) + ((size_t)dh << 5);
  #pragma unroll
  for (int r = 0; r < 16; ++r) {
    int idx = r * 256 + tid;
    int ci = idx >> 5, w = idx & 31;
    lds[w][ci] = in[planebase + ((size_t)ci << 15) + w];
  }
  __syncthreads();
  size_t tb = ((size_t)blk) << 5;
  #pragma unroll
  for (int r = 0; r < 16; ++r) {
    int idx = r * 256 + tid;
    int w = idx >> 7, ci = idx & 127;
    outT[(tb + w) * 128 + ci] = lds[w][ci];
  }
}

// ---------------------------------------------------------------------------
// K1: 3x3x3 circular conv via bf16 MFMA (fp32 accumulate)
// ---------------------------------------------------------------------------
__global__ __launch_bounds__(256) void conv_mfma_kernel(const unsigned short* __restrict__ inT,
                                                        const unsigned short* __restrict__ Bp,
                                                        const float* __restrict__ b1,
                                                        float* __restrict__ out) {
  __shared__ unsigned short Als[16384];  // 32 KB: 128 tok x 128 ci bf16, swizzled
  const int blk = blockIdx.x;
  const int b = blk >> 8, d = (blk >> 3) & 31, hg = blk & 7;
  const int h0 = hg << 2;
  const int tid = threadIdx.x;
  const int lane = tid & 63, wid = tid >> 6;
  const int wm = wid >> 1, wn = wid & 1;
  const int l15 = lane & 15, l4 = lane >> 4;

  f32x4 acc[4][4];
  #pragma unroll
  for (int mt = 0; mt < 4; ++mt)
    #pragma unroll
    for (int nt = 0; nt < 4; ++nt)
      #pragma unroll
      for (int r = 0; r < 4; ++r) acc[mt][nt][r] = 0.f;

  int mw[4], mhh[4];
  #pragma unroll
  for (int mt = 0; mt < 4; ++mt) {
    int m = wm * 64 + mt * 16 + l15;
    mhh[mt] = m >> 5;
    mw[mt] = m & 31;
  }
  const size_t tokbase = ((size_t)b << 15) + ((size_t)d << 10) + ((size_t)h0 << 5);

  for (int tap = 0; tap < 9; ++tap) {
    const int dz = tap / 3, dy = tap % 3;
    const int zr = (d + dz + 31) & 31;
    __syncthreads();
    #pragma unroll
    for (int p = 0; p < 8; ++p) {
      int g = p * 256 + tid;
      int tok = g >> 4, gi = g & 15;
      int hh = tok >> 5, w = tok & 31;
      int yr = (h0 + hh + dy + 31) & 31;
      size_t srcbyte = ((((size_t)b << 15) + ((size_t)zr << 10) + ((size_t)yr << 5) + w) << 8)
                       + (size_t)((gi ^ (w & 7)) << 4);
      uint4 v = *(const uint4*)((const char*)inT + srcbyte);
      *(uint4*)((char*)Als + g * 16) = v;
    }
    __syncthreads();
    int brow[4];
    #pragma unroll
    for (int nt = 0; nt < 4; ++nt) {
      int co = wn * 64 + nt * 16 + l15;
      brow[nt] = (tap * 128 + co) * 384;
    }
    #pragma unroll
    for (int dx = 0; dx < 3; ++dx) {
      int abase[4], asw[4];
      #pragma unroll
      for (int mt = 0; mt < 4; ++mt) {
        int wsft = (mw[mt] + dx + 31) & 31;
        int stok = mhh[mt] * 32 + wsft;
        abase[mt] = stok * 256;
        asw[mt] = (stok & 7) << 4;
      }
      #pragma unroll
      for (int ks = 0; ks < 4; ++ks) {
        const int k2 = (ks * 32 + l4 * 8) * 2;
        const int koff = dx * 128 + ks * 32 + l4 * 8;
        short8 afr[4], bfr[4];
        #pragma unroll
        for (int mt = 0; mt < 4; ++mt)
          afr[mt] = *(const short8*)((const char*)Als + abase[mt] + (k2 ^ asw[mt]));
        #pragma unroll
        for (int nt = 0; nt < 4; ++nt)
          bfr[nt] = *(const short8*)(Bp + brow[nt] + koff);
        #pragma unroll
        for (int mt = 0; mt < 4; ++mt)
          #pragma unroll
          for (int nt = 0; nt < 4; ++nt)
            acc[mt][nt] = __builtin_amdgcn_mfma_f32_16x16x32_bf16(afr[mt], bfr[nt],
                                                                  acc[mt][nt], 0, 0, 0);
      }
    }
  }
  #pragma unroll
  for (int nt = 0; nt < 4; ++nt) {
    const int co = wn * 64 + nt * 16 + l15;
    const float bias = b1[co];
    #pragma unroll
    for (int mt = 0; mt < 4; ++mt) {
      #pragma unroll
      for (int r = 0; r < 4; ++r) {
        int m = wm * 64 + mt * 16 + l4 * 4 + r;
        out[(tokbase + m) * 128 + co] = acc[mt][nt][r] + bias;
      }
    }
  }
}

// ---------------------------------------------------------------------------
// K2: instance-norm partial sums (deterministic two-pass)
// ---------------------------------------------------------------------------
__global__ __launch_bounds__(256) void stats_partial_kernel(const float* __restrict__ buf,
                                                            float* __restrict__ ps,
                                                            float* __restrict__ pss) {
  __shared__ float l1[256], l2[256];
  int blk = blockIdx.x;
  int tid = threadIdx.x;
  int c = tid & 127, half = tid >> 7;
  size_t t0 = (size_t)blk * 256;
  float s = 0.f, ss = 0.f;
  for (int i = half; i < 256; i += 2) {
    float v = buf[(t0 + i) * 128 + c];
    s += v;
    ss += v * v;
  }
  l1[tid] = s; l2[tid] = ss;
  __syncthreads();
  if (half == 0) {
    ps[blk * 128 + c] = s + l1[tid + 128];
    pss[blk * 128 + c] = ss + l2[tid + 128];
  }
}

__global__ void stats_final_kernel(const float* __restrict__ ps, const float* __restrict__ pss,
                                   float* __restrict__ mu, float* __restrict__ rs) {
  int tid = threadIdx.x;  // tid = b*128 + c
  int b = tid >> 7, c = tid & 127;
  float s = 0.f, ss = 0.f;
  for (int blk = b * 128; blk < b * 128 + 128; ++blk) {
    s += ps[blk * 128 + c];
    ss += pss[blk * 128 + c];
  }
  float m = s * (1.0f / 32768.0f);
  float v = ss * (1.0f / 32768.0f) - m * m;
  mu[tid] = m;
  rs[tid] = rsqrtf(v + 1e-5f);
}

// ---------------------------------------------------------------------------
// K3: 1x1 GEMM via bf16 MFMA, register-only (no LDS).
// D[t][o] = post( pre(A[t][:]) @ Wp[o][:]^T + bias[o] )
// PRE: 0 none | 1 gelu(inorm)   POST: 0 plain store | 1 sigmoid*x store
// Block: 128 tokens x 128 o; 4 waves 2x2, each 64x64. grid (O/128, NTOK/128)
// ---------------------------------------------------------------------------
template <int PRE, int POST>
__global__ __launch_bounds__(256) void gemm_mfma_kernel(
    const float* __restrict__ Ap, const unsigned short* __restrict__ Wp,
    const float* __restrict__ bias, float* __restrict__ Y, int O,
    const float* __restrict__ mu, const float* __restrict__ rs,
    const float* __restrict__ xt) {
  const int tid = threadIdx.x;
  const int lane = tid & 63, wid = tid >> 6;
  const int wm = wid >> 1, wn = wid & 1;
  const int l15 = lane & 15, l4 = lane >> 4;
  const int og = blockIdx.x * 128;
  const int t0 = blockIdx.y * 128;
  const int bidx = t0 >> 15;

  f32x4 acc[4][4];
  #pragma unroll
  for (int mt = 0; mt < 4; ++mt)
    #pragma unroll
    for (int nt = 0; nt < 4; ++nt)
      #pragma unroll
      for (int r = 0; r < 4; ++r) acc[mt][nt][r] = 0.f;

  #pragma unroll
  for (int ks = 0; ks < 4; ++ks) {
    const int kb = ks * 32 + l4 * 8;
    short8 a[4], b[4];
    float4 m0, m1, r0, r1;
    if constexpr (PRE == 1) {
      m0 = *(const float4*)(mu + bidx * 128 + kb);
      m1 = *(const float4*)(mu + bidx * 128 + kb + 4);
      r0 = *(const float4*)(rs + bidx * 128 + kb);
      r1 = *(const float4*)(rs + bidx * 128 + kb + 4);
    }
    #pragma unroll
    for (int mt = 0; mt < 4; ++mt) {
      const int tok = t0 + wm * 64 + mt * 16 + l15;
      const float* ap = Ap + (size_t)tok * 128 + kb;
      float4 v0 = *(const float4*)ap;
      float4 v1 = *(const float4*)(ap + 4);
      if constexpr (PRE == 1) {
        v0.x = gelu_f((v0.x - m0.x) * r0.x);
        v0.y = gelu_f((v0.y - m0.y) * r0.y);
        v0.z = gelu_f((v0.z - m0.z) * r0.z);
        v0.w = gelu_f((v0.w - m0.w) * r0.w);
        v1.x = gelu_f((v1.x - m1.x) * r1.x);
        v1.y = gelu_f((v1.y - m1.y) * r1.y);
        v1.z = gelu_f((v1.z - m1.z) * r1.z);
        v1.w = gelu_f((v1.w - m1.w) * r1.w);
      }
      a[mt] = pack_bf8(v0, v1);
    }
    #pragma unroll
    for (int nt = 0; nt < 4; ++nt) {
      const int o = og + wn * 64 + nt * 16 + l15;
      b[nt] = *(const short8*)(Wp + (size_t)o * 128 + kb);
    }
    #pragma unroll
    for (int mt = 0; mt < 4; ++mt)
      #pragma unroll
      for (int nt = 0; nt < 4; ++nt)
        acc[mt][nt] = __builtin_amdgcn_mfma_f32_16x16x32_bf16(a[mt], b[nt], acc[mt][nt], 0, 0, 0);
  }

  #pragma unroll
  for (int nt = 0; nt < 4; ++nt) {
    const int o = og + wn * 64 + nt * 16 + l15;
    const float bb = bias[o];
    #pragma unroll
    for (int mt = 0; mt < 4; ++mt) {
      #pragma unroll
      for (int r = 0; r < 4; ++r) {
        const int t = t0 + wm * 64 + mt * 16 + l4 * 4 + r;
        float v = acc[mt][nt][r] + bb;
        if constexpr (POST == 1) {
          v = sigmoid_f(v) * xt[(size_t)t * 128 + o];
          Y[(size_t)t * 128 + o] = v;
        } else {
          Y[(size_t)t * O + o] = v;
        }
      }
    }
  }
}

// ---------------------------------------------------------------------------
// K6: final projection, swapped orientation: D[o][token] = W[o][k] x Acc^T
// -> NCDHW stores coalesced (16 consecutive tokens per 16-lane group)
// ---------------------------------------------------------------------------
__global__ __launch_bounds__(256) void proj_mfma_kernel(
    const float* __restrict__ Acc, const unsigned short* __restrict__ Wp,
    const float* __restrict__ bias, float* __restrict__ out) {
  const int tid = threadIdx.x;
  const int lane = tid & 63, wid = tid >> 6;
  const int wm = wid >> 1, wn = wid & 1;  // wm: o half, wn: token half
  const int l15 = lane & 15, l4 = lane >> 4;
  const int t0 = blockIdx.x * 128;

  f32x4 acc[4][4];
  #pragma unroll
  for (int mt = 0; mt < 4; ++mt)
    #pragma unroll
    for (int nt = 0; nt < 4; ++nt)
      #pragma unroll
      for (int r = 0; r < 4; ++r) acc[mt][nt][r] = 0.f;

  #pragma unroll
  for (int ks = 0; ks < 4; ++ks) {
    const int kb = ks * 32 + l4 * 8;
    short8 a[4], b[4];
    #pragma unroll
    for (int mt = 0; mt < 4; ++mt) {
      const int o = wm * 64 + mt * 16 + l15;
      a[mt] = *(const short8*)(Wp + (size_t)o * 128 + kb);
    }
    #pragma unroll
    for (int nt = 0; nt < 4; ++nt) {
      const int tok = t0 + wn * 64 + nt * 16 + l15;
      const float* bp = Acc + (size_t)tok * 128 + kb;
      b[nt] = pack_bf8(*(const float4*)bp, *(const float4*)(bp + 4));
    }
    #pragma unroll
    for (int mt = 0; mt < 4; ++mt)
      #pragma unroll
      for (int nt = 0; nt < 4; ++nt)
        acc[mt][nt] = __builtin_amdgcn_mfma_f32_16x16x32_bf16(a[mt], b[nt], acc[mt][nt], 0, 0, 0);
  }

  #pragma unroll
  for (int nt = 0; nt < 4; ++nt) {
    const int tok = t0 + wn * 64 + nt * 16 + l15;
    const int dhw = tok & 32767, bB = tok >> 15;
    #pragma unroll
    for (int mt = 0; mt < 4; ++mt) {
      #pragma unroll
      for (int r = 0; r < 4; ++r) {
        const int o = wm * 64 + mt * 16 + l4 * 4 + r;
        out[((size_t)(bB * 128 + o) << 15) + dhw] = acc[mt][nt][r] + bias[o];
      }
    }
  }
}

// ---------------------------------------------------------------------------
// K7: axial attention (fp32). One wave per (seq, head-pair).
// Effective logit: q_r.k_r * 0.25 - lin[k] * pos_bias_w[comp]
// ---------------------------------------------------------------------------
__device__ __forceinline__ void rot16(const float* R, const float* x, float* y) {
  #pragma unroll
  for (int g = 0; g < 5; ++g) {
    float a = x[3 * g], b = x[3 * g + 1], c = x[3 * g + 2];
    y[3 * g + 0] = R[0] * a + R[1] * b + R[2] * c;
    y[3 * g + 1] = R[3] * a + R[4] * b + R[5] * c;
    y[3 * g + 2] = R[6] * a + R[7] * b + R[8] * c;
  }
  y[15] = R[0] * x[15];  // padded vector (x15,0,0): only row0 col0 survives
}

template <int ACCUM>
__global__ __launch_bounds__(64) void attn_kernel(const float* __restrict__ qkv,
                                                  const float* __restrict__ Rbuf,
                                                  const float* __restrict__ pbw,
                                                  float* __restrict__ accum, int axial) {
  __shared__ float Klds[2][32][20];
  __shared__ float Vlds[2][32][20];
  int seq = blockIdx.x, hp = blockIdx.y;
  int lane = threadIdx.x;
  int hh = lane >> 5;
  int head = hp * 2 + hh;
  int tok = lane & 31;
  int b = seq >> 10, rem = seq & 1023;
  int u = rem >> 5, v = rem & 31;
  int base, stride, comp;
  if (axial == 0) { base = (b << 15) + (u << 5) + v;  stride = 1024; comp = 2; }
  else if (axial == 1) { base = (b << 15) + (u << 10) + v; stride = 32; comp = 1; }
  else { base = (b << 15) + (u << 10) + (v << 5); stride = 1; comp = 0; }
  const float* Rp = Rbuf + (axial * 8 + head) * 18;
  float Rq[9], Rv[9];
  #pragma unroll
  for (int i = 0; i < 9; ++i) { Rq[i] = Rp[i]; Rv[i] = Rp[9 + i]; }
  size_t t_tok = (size_t)base + (size_t)tok * stride;
  const float* row = qkv + t_tok * 384 + head * 16;
  float xq[16], xk[16], xv[16];
  #pragma unroll
  for (int j = 0; j < 4; ++j) {
    float4 a = *(const float4*)(row + j * 4);
    float4 bq = *(const float4*)(row + 128 + j * 4);
    float4 cq = *(const float4*)(row + 256 + j * 4);
    xq[j * 4] = a.x; xq[j * 4 + 1] = a.y; xq[j * 4 + 2] = a.z; xq[j * 4 + 3] = a.w;
    xk[j * 4] = bq.x; xk[j * 4 + 1] = bq.y; xk[j * 4 + 2] = bq.z; xk[j * 4 + 3] = bq.w;
    xv[j * 4] = cq.x; xv[j * 4 + 1] = cq.y; xv[j * 4 + 2] = cq.z; xv[j * 4 + 3] = cq.w;
  }
  float qr[16], kr[16], vr[16];
  rot16(Rq, xq, qr);
  rot16(Rq, xk, kr);
  rot16(Rv, xv, vr);
  #pragma unroll
  for (int j = 0; j < 16; ++j) { Klds[hh][tok][j] = kr[j]; Vlds[hh][tok][j] = vr[j]; }
  __syncthreads();
  float wb = pbw[comp];
  float s[32];
  #pragma unroll
  for (int k = 0; k < 32; ++k) {
    const float* kp = &Klds[hh][k][0];
    float dot = 0.f;
    #pragma unroll
    for (int j = 0; j < 16; ++j) dot += qr[j] * kp[j];
    float lin = -1.0f + (2.0f / 31.0f) * (float)k;
    s[k] = dot * 0.25f - lin * wb;
  }
  float m = s[0];
  #pragma unroll
  for (int k = 1; k < 32; ++k) m = fmaxf(m, s[k]);
  float sum = 0.f;
  #pragma unroll
  for (int k = 0; k < 32; ++k) { s[k] = expf(s[k] - m); sum += s[k]; }
  float inv = 1.0f / sum;
  float o[16];
  #pragma unroll
  for (int j = 0; j < 16; ++j) o[j] = 0.f;
  #pragma unroll
  for (int k = 0; k < 32; ++k) {
    float p = s[k];
    const float* vp = &Vlds[hh][k][0];
    #pragma unroll
    for (int j = 0; j < 16; ++j) o[j] += p * vp[j];
  }
  float* dst = accum + t_tok * 128 + head * 16;
  if (ACCUM == 0) {
    #pragma unroll
    for (int j = 0; j < 16; ++j) dst[j] = o[j] * inv;
  } else {
    #pragma unroll
    for (int j = 0; j < 16; ++j) dst[j] += o[j] * inv;
  }
}

// ---------------------------------------------------------------------------
extern "C" void kernel_launch(void* const* d_in, const int* in_sizes, int n_in,
                              void* d_out, int out_size, void* d_ws, size_t ws_size,
                              hipStream_t stream) {
  const float* x       = (const float*)d_in[0];
  const float* pos_emb = (const float*)d_in[1];
  const float* qkv_w   = (const float*)d_in[2];
  const float* qkv_b   = (const float*)d_in[3];
  const float* lp_w1   = (const float*)d_in[4];
  const float* lp_b1   = (const float*)d_in[5];
  const float* lp_w2   = (const float*)d_in[6];
  const float* lp_b2   = (const float*)d_in[7];
  const float* mod_w1  = (const float*)d_in[8];
  const float* mod_b1  = (const float*)d_in[9];
  const float* mod_w2  = (const float*)d_in[10];
  const float* mod_b2  = (const float*)d_in[11];
  // d_in[12] pa_w, d_in[13] pa_b: cancel in softmax (constant along key axis)
  const float* proj_w  = (const float*)d_in[14];
  const float* proj_b  = (const float*)d_in[15];
  const float* pbw     = (const float*)d_in[16];
  // d_in[17] pos_bias_b: cancels in softmax
  const float* Ad      = (const float*)d_in[18];
  const float* Ah      = (const float*)d_in[19];
  const float* Aw      = (const float*)d_in[20];
  const float* Rd      = (const float*)d_in[21];
  const float* Rh      = (const float*)d_in[22];
  const float* Rw      = (const float*)d_in[23];
  // d_in[24..26] t_d/t_h/t_w: cancel in rel (pairwise difference)

  float* ws = (float*)d_ws;
  float* R0     = ws + WS_R0;     // lf -> x_mod -> attn accum
  float* mpre   = ws + WS_MPRE;
  float* xtok   = ws + WS_XTOK;
  float* qkv    = ws + WS_QKV;
  unsigned short* inT    = (unsigned short*)(ws + WS_INT);
  unsigned short* convP  = (unsigned short*)(ws + WS_CONVP);
  unsigned short* qkvP   = (unsigned short*)(ws + WS_QKVP);
  unsigned short* WcP    = (unsigned short*)(ws + WS_WCP);
  unsigned short* modw2P = (unsigned short*)(ws + WS_MODW2P);
  unsigned short* projP  = (unsigned short*)(ws + WS_PROJP);
  float* bc     = ws + WS_BC;
  float* Rbuf   = ws + WS_RBUF;
  float* ps     = ws + WS_PS;
  float* pss    = ws + WS_PSS;
  float* mu1    = ws + WS_MU1;
  float* rs1    = ws + WS_RS1;
  float* mu2    = ws + WS_MU2;
  float* rs2    = ws + WS_RS2;

  prep_r_kernel<<<1, 64, 0, stream>>>(Ad, Ah, Aw, Rd, Rh, Rw, Rbuf);
  prep_w_kernel<<<256, 256, 0, stream>>>(lp_w1, qkv_w, mod_w1, lp_w2, lp_b2, mod_b1,
                                         mod_w2, proj_w, convP, qkvP, WcP, modw2P, projP, bc);
  tobf16_kernel<<<2048, 256, 0, stream>>>(pos_emb, inT);
  xT_kernel<<<2048, 256, 0, stream>>>(x, xtok);
  // lf = circular conv3x3x3(pos_emb), bf16 MFMA
  conv_mfma_kernel<<<512, 256, 0, stream>>>(inT, convP, lp_b1, R0);
  // m_pre = gelu(inorm(lf)) @ Wc^T + bc
  stats_partial_kernel<<<256, 256, 0, stream>>>(R0, ps, pss);
  stats_final_kernel<<<1, 256, 0, stream>>>(ps, pss, mu1, rs1);
  gemm_mfma_kernel<1, 0><<<dim3(1, 512), 256, 0, stream>>>(R0, WcP, bc, mpre, 128, mu1, rs1, nullptr);
  // x_mod = x * sigmoid(gelu(inorm(m_pre)) @ mod_w2^T + mod_b2)
  stats_partial_kernel<<<256, 256, 0, stream>>>(mpre, ps, pss);
  stats_final_kernel<<<1, 256, 0, stream>>>(ps, pss, mu2, rs2);
  gemm_mfma_kernel<1, 1><<<dim3(1, 512), 256, 0, stream>>>(mpre, modw2P, mod_b2, R0, 128, mu2, rs2, xtok);
  // qkv = x_mod @ qkv_w^T + qkv_b
  gemm_mfma_kernel<0, 0><<<dim3(3, 512), 256, 0, stream>>>(R0, qkvP, qkv_b, qkv, 384, nullptr, nullptr, nullptr);
  // three axial attentions, accumulated into R0 (x_mod dead after qkv gemm)
  attn_kernel<0><<<dim3(2048, 4), 64, 0, stream>>>(qkv, Rbuf, pbw, R0, 0);
  attn_kernel<1><<<dim3(2048, 4), 64, 0, stream>>>(qkv, Rbuf, pbw, R0, 1);
  attn_kernel<1><<<dim3(2048, 4), 64, 0, stream>>>(qkv, Rbuf, pbw, R0, 2);
  // final projection -> NCDHW output (transposed orientation, coalesced stores)
  proj_mfma_kernel<<<512, 256, 0, stream>>>(R0, projP, proj_b, (float*)d_out);
}